// Round 1
// baseline (589.086 us; speedup 1.0000x reference)
//
#include <hip/hip_runtime.h>

#define NN 50000
#define D 128

// ---------------------------------------------------------------------------
// Kernel 1: one wave (64 lanes) per edge.
//   gather feature[src] (coalesced float2/lane = 512B/wave)
//   atomicAdd into agg[dst]  (agg lives in d_out)
//   lane 0 bumps deg[dst]
// ---------------------------------------------------------------------------
__global__ void gcn_scatter(const float* __restrict__ feature,
                            const int* __restrict__ src,
                            const int* __restrict__ dst,
                            float* __restrict__ agg,
                            float* __restrict__ deg,
                            int n_edges) {
    int gid  = blockIdx.x * blockDim.x + threadIdx.x;
    int e    = gid >> 6;
    int lane = gid & 63;
    if (e >= n_edges) return;
    int s = src[e];
    int d = dst[e];
    const float2 v =
        *reinterpret_cast<const float2*>(feature + (size_t)s * D + lane * 2);
    float* o = agg + (size_t)d * D + lane * 2;
    atomicAdd(o, v.x);
    atomicAdd(o + 1, v.y);
    if (lane == 0) atomicAdd(deg + d, 1.0f);
}

// ---------------------------------------------------------------------------
// Kernel 2: finalize.  W (128x128 f32 = 64KB) + b staged in LDS.
// Each wave processes 4 node rows at a time:
//   h = deg>0 ? agg/deg : feature      (agg read from d_out)
//   out = relu(h @ W + b)              (written in-place to d_out)
// 4 rows/wave amortizes the W LDS reads 4x. Lane j owns cols j and j+64.
// ---------------------------------------------------------------------------
__global__ __launch_bounds__(256, 2) void gcn_finalize(
    float* __restrict__ inout,
    const float* __restrict__ feature,
    const float* __restrict__ W,
    const float* __restrict__ b,
    const float* __restrict__ deg,
    int n_nodes) {
    __shared__ float Ws[D * D];
    __shared__ float bs[D];
    __shared__ float hs[4][4][D];  // [wave][row-in-group][k]

    for (int i = threadIdx.x; i < (D * D) / 4; i += blockDim.x)
        reinterpret_cast<float4*>(Ws)[i] = reinterpret_cast<const float4*>(W)[i];
    if (threadIdx.x < D) bs[threadIdx.x] = b[threadIdx.x];
    __syncthreads();

    int wave   = threadIdx.x >> 6;
    int lane   = threadIdx.x & 63;
    int gwave  = (blockIdx.x * blockDim.x + threadIdx.x) >> 6;
    int nwaves = (gridDim.x * blockDim.x) >> 6;
    int ngroups = (n_nodes + 3) / 4;

    for (int g = gwave; g < ngroups; g += nwaves) {
        int row0 = g * 4;
        // stage 4 h-rows into wave-private LDS (no barrier needed)
        #pragma unroll
        for (int r = 0; r < 4; ++r) {
            int row = row0 + r;
            if (row < n_nodes) {
                float dg = deg[row];
                float2 h2;
                if (dg > 0.f) {
                    float2 a = *reinterpret_cast<const float2*>(
                        inout + (size_t)row * D + lane * 2);
                    float rd = 1.f / dg;
                    h2.x = a.x * rd;
                    h2.y = a.y * rd;
                } else {
                    h2 = *reinterpret_cast<const float2*>(
                        feature + (size_t)row * D + lane * 2);
                }
                reinterpret_cast<float2*>(hs[wave][r])[lane] = h2;
            }
        }

        float acc[4][2];
        #pragma unroll
        for (int r = 0; r < 4; ++r) {
            acc[r][0] = bs[lane];
            acc[r][1] = bs[lane + 64];
        }

        #pragma unroll 4
        for (int k = 0; k < D; ++k) {
            float w0 = Ws[k * D + lane];       // 2-way bank alias: free
            float w1 = Ws[k * D + lane + 64];
            #pragma unroll
            for (int r = 0; r < 4; ++r) {
                float hk = hs[wave][r][k];     // broadcast: free
                acc[r][0] = fmaf(hk, w0, acc[r][0]);
                acc[r][1] = fmaf(hk, w1, acc[r][1]);
            }
        }

        #pragma unroll
        for (int r = 0; r < 4; ++r) {
            int row = row0 + r;
            if (row < n_nodes) {
                inout[(size_t)row * D + lane]      = fmaxf(acc[r][0], 0.f);
                inout[(size_t)row * D + lane + 64] = fmaxf(acc[r][1], 0.f);
            }
        }
    }
}

extern "C" void kernel_launch(void* const* d_in, const int* in_sizes, int n_in,
                              void* d_out, int out_size, void* d_ws, size_t ws_size,
                              hipStream_t stream) {
    const float* feature = (const float*)d_in[0];
    const float* W       = (const float*)d_in[1];
    const float* b       = (const float*)d_in[2];
    const int*   src     = (const int*)d_in[3];
    const int*   dst     = (const int*)d_in[4];
    int n_edges = in_sizes[3];
    int n_nodes = in_sizes[0] / D;

    float* agg = (float*)d_out;      // agg accumulates in d_out, finalized in-place
    float* deg = (float*)d_ws;       // [n_nodes] f32

    hipMemsetAsync(agg, 0, (size_t)out_size * sizeof(float), stream);
    hipMemsetAsync(deg, 0, (size_t)n_nodes * sizeof(float), stream);

    {
        long long total_threads = (long long)n_edges * 64;
        int block = 256;
        int grid = (int)((total_threads + block - 1) / block);
        gcn_scatter<<<grid, block, 0, stream>>>(feature, src, dst, agg, deg,
                                                n_edges);
    }
    {
        int block = 256;
        int grid = 512;  // 2 blocks/CU resident (72.5KB LDS each)
        gcn_finalize<<<grid, block, 0, stream>>>(agg, feature, W, b, deg,
                                                 n_nodes);
    }
}

// Round 2
// 170.090 us; speedup vs baseline: 3.4634x; 3.4634x over previous
//
#include <hip/hip_runtime.h>

#define D 128

// ===========================================================================
// CSR-build path (no float atomics)
// ===========================================================================

// K1: histogram of dst -> cnt[]
__global__ void k_hist(const int* __restrict__ dst, int* __restrict__ cnt,
                       int E) {
    int stride = gridDim.x * blockDim.x;
    for (int i = blockIdx.x * blockDim.x + threadIdx.x; i < E; i += stride)
        atomicAdd(&cnt[dst[i]], 1);
}

// K2: bucket base allocation. Order of buckets is irrelevant, so allocate
// with a wave-aggregated atomic bump on a single counter (782 atomics total).
__global__ void k_alloc(const int* __restrict__ cnt, int* __restrict__ offset,
                        int* __restrict__ cursor, int* __restrict__ gtot,
                        int N) {
    int i = blockIdx.x * blockDim.x + threadIdx.x;
    int lane = threadIdx.x & 63;
    int c = (i < N) ? cnt[i] : 0;
    int s = c;  // wave inclusive scan
    #pragma unroll
    for (int o = 1; o < 64; o <<= 1) {
        int t = __shfl_up(s, o);
        if (lane >= o) s += t;
    }
    int wavesum = __shfl(s, 63);
    int base = 0;
    if (lane == 0) base = atomicAdd(gtot, wavesum);
    base = __shfl(base, 0);
    if (i < N) {
        int off = base + s - c;
        offset[i] = off;
        cursor[i] = off;
    }
}

// K3: fill buckets with source node ids
__global__ void k_fill(const int* __restrict__ src, const int* __restrict__ dst,
                       int* __restrict__ cursor, int* __restrict__ srcs,
                       int E) {
    int stride = gridDim.x * blockDim.x;
    for (int i = blockIdx.x * blockDim.x + threadIdx.x; i < E; i += stride) {
        int d = dst[i];
        int p = atomicAdd(&cursor[d], 1);
        srcs[p] = src[i];
    }
}

// K4: one wave per node: mean of gathered feature[src] rows (or copy own
// feature row when no in-edges). Lane j owns cols 2j, 2j+1.
__global__ __launch_bounds__(256) void k_aggregate(
    const float* __restrict__ feature, const int* __restrict__ srcs,
    const int* __restrict__ offset, const int* __restrict__ cnt,
    float* __restrict__ h, int N) {
    int w = (blockIdx.x * blockDim.x + threadIdx.x) >> 6;
    int lane = threadIdx.x & 63;
    if (w >= N) return;
    int n = __builtin_amdgcn_readfirstlane(cnt[w]);
    float2 acc = make_float2(0.f, 0.f);
    if (n == 0) {
        acc = *reinterpret_cast<const float2*>(feature + (size_t)w * D +
                                               lane * 2);
    } else {
        int base = __builtin_amdgcn_readfirstlane(offset[w]);
        int j = 0;
        for (; j + 4 <= n; j += 4) {
            int s0 = srcs[base + j + 0];
            int s1 = srcs[base + j + 1];
            int s2 = srcs[base + j + 2];
            int s3 = srcs[base + j + 3];
            float2 v0 = *reinterpret_cast<const float2*>(feature + (size_t)s0 * D + lane * 2);
            float2 v1 = *reinterpret_cast<const float2*>(feature + (size_t)s1 * D + lane * 2);
            float2 v2 = *reinterpret_cast<const float2*>(feature + (size_t)s2 * D + lane * 2);
            float2 v3 = *reinterpret_cast<const float2*>(feature + (size_t)s3 * D + lane * 2);
            acc.x += (v0.x + v1.x) + (v2.x + v3.x);
            acc.y += (v0.y + v1.y) + (v2.y + v3.y);
        }
        for (; j < n; ++j) {
            int s0 = srcs[base + j];
            float2 v0 = *reinterpret_cast<const float2*>(feature + (size_t)s0 * D + lane * 2);
            acc.x += v0.x;
            acc.y += v0.y;
        }
        float r = 1.f / (float)n;
        acc.x *= r;
        acc.y *= r;
    }
    *reinterpret_cast<float2*>(h + (size_t)w * D + lane * 2) = acc;
}

// ===========================================================================
// Fallback path (small workspace): float-atomic scatter (round-1 kernel)
// ===========================================================================
__global__ void gcn_scatter(const float* __restrict__ feature,
                            const int* __restrict__ src,
                            const int* __restrict__ dst,
                            float* __restrict__ agg,
                            float* __restrict__ deg, int n_edges) {
    int gid = blockIdx.x * blockDim.x + threadIdx.x;
    int e = gid >> 6;
    int lane = gid & 63;
    if (e >= n_edges) return;
    int s = src[e];
    int d = dst[e];
    const float2 v =
        *reinterpret_cast<const float2*>(feature + (size_t)s * D + lane * 2);
    float* o = agg + (size_t)d * D + lane * 2;
    atomicAdd(o, v.x);
    atomicAdd(o + 1, v.y);
    if (lane == 0) atomicAdd(deg + d, 1.0f);
}

// ===========================================================================
// Finalize: out = relu(h @ W + b), in place on `inout`.
// If deg != nullptr, first h = deg>0 ? inout/deg : feature (fallback path);
// else inout already holds h (CSR path).
// ===========================================================================
__global__ __launch_bounds__(256, 2) void gcn_finalize(
    float* __restrict__ inout, const float* __restrict__ feature,
    const float* __restrict__ W, const float* __restrict__ b,
    const float* __restrict__ deg, int n_nodes) {
    __shared__ float Ws[D * D];
    __shared__ float bs[D];
    __shared__ float hs[4][4][D];  // [wave][row-in-group][k]

    for (int i = threadIdx.x; i < (D * D) / 4; i += blockDim.x)
        reinterpret_cast<float4*>(Ws)[i] = reinterpret_cast<const float4*>(W)[i];
    if (threadIdx.x < D) bs[threadIdx.x] = b[threadIdx.x];
    __syncthreads();

    int wave = threadIdx.x >> 6;
    int lane = threadIdx.x & 63;
    int gwave = (blockIdx.x * blockDim.x + threadIdx.x) >> 6;
    int nwaves = (gridDim.x * blockDim.x) >> 6;
    int ngroups = (n_nodes + 3) / 4;

    for (int g = gwave; g < ngroups; g += nwaves) {
        int row0 = g * 4;
        #pragma unroll
        for (int r = 0; r < 4; ++r) {
            int row = row0 + r;
            if (row < n_nodes) {
                float2 h2;
                if (deg) {
                    float dg = deg[row];
                    if (dg > 0.f) {
                        float2 a = *reinterpret_cast<const float2*>(
                            inout + (size_t)row * D + lane * 2);
                        float rd = 1.f / dg;
                        h2.x = a.x * rd;
                        h2.y = a.y * rd;
                    } else {
                        h2 = *reinterpret_cast<const float2*>(
                            feature + (size_t)row * D + lane * 2);
                    }
                } else {
                    h2 = *reinterpret_cast<const float2*>(inout +
                                                          (size_t)row * D +
                                                          lane * 2);
                }
                reinterpret_cast<float2*>(hs[wave][r])[lane] = h2;
            }
        }

        float acc[4][2];
        #pragma unroll
        for (int r = 0; r < 4; ++r) {
            acc[r][0] = bs[lane];
            acc[r][1] = bs[lane + 64];
        }

        #pragma unroll 4
        for (int k = 0; k < D; ++k) {
            float w0 = Ws[k * D + lane];
            float w1 = Ws[k * D + lane + 64];
            #pragma unroll
            for (int r = 0; r < 4; ++r) {
                float hk = hs[wave][r][k];
                acc[r][0] = fmaf(hk, w0, acc[r][0]);
                acc[r][1] = fmaf(hk, w1, acc[r][1]);
            }
        }

        #pragma unroll
        for (int r = 0; r < 4; ++r) {
            int row = row0 + r;
            if (row < n_nodes) {
                inout[(size_t)row * D + lane] = fmaxf(acc[r][0], 0.f);
                inout[(size_t)row * D + lane + 64] = fmaxf(acc[r][1], 0.f);
            }
        }
    }
}

extern "C" void kernel_launch(void* const* d_in, const int* in_sizes, int n_in,
                              void* d_out, int out_size, void* d_ws,
                              size_t ws_size, hipStream_t stream) {
    const float* feature = (const float*)d_in[0];
    const float* W = (const float*)d_in[1];
    const float* b = (const float*)d_in[2];
    const int* src = (const int*)d_in[3];
    const int* dst = (const int*)d_in[4];
    int n_edges = in_sizes[3];
    int n_nodes = in_sizes[0] / D;

    float* out = (float*)d_out;

    // workspace layout (ints): cnt[N] | gtot[1] | offset[N] | cursor[N] | srcs[E]
    size_t need = ((size_t)3 * n_nodes + 1 + n_edges) * sizeof(int);

    if (ws_size >= need) {
        int* cnt = (int*)d_ws;
        int* gtot = cnt + n_nodes;
        int* offset = gtot + 1;
        int* cursor = offset + n_nodes;
        int* srcs = cursor + n_nodes;

        hipMemsetAsync(cnt, 0, (size_t)(n_nodes + 1) * sizeof(int), stream);

        int block = 256;
        k_hist<<<2048, block, 0, stream>>>(dst, cnt, n_edges);
        k_alloc<<<(n_nodes + block - 1) / block, block, 0, stream>>>(
            cnt, offset, cursor, gtot, n_nodes);
        k_fill<<<2048, block, 0, stream>>>(src, dst, cursor, srcs, n_edges);
        k_aggregate<<<(n_nodes * 64 + block - 1) / block, block, 0, stream>>>(
            feature, srcs, offset, cnt, out, n_nodes);
        gcn_finalize<<<512, block, 0, stream>>>(out, feature, W, b, nullptr,
                                                n_nodes);
    } else {
        // fallback: float-atomic scatter
        float* deg = (float*)d_ws;  // [n_nodes]
        hipMemsetAsync(out, 0, (size_t)out_size * sizeof(float), stream);
        hipMemsetAsync(deg, 0, (size_t)n_nodes * sizeof(float), stream);
        long long total_threads = (long long)n_edges * 64;
        int block = 256;
        int grid = (int)((total_threads + block - 1) / block);
        gcn_scatter<<<grid, block, 0, stream>>>(feature, src, dst, out, deg,
                                                n_edges);
        gcn_finalize<<<512, block, 0, stream>>>(out, feature, W, b, deg,
                                                n_nodes);
    }
}

// Round 3
// 145.523 us; speedup vs baseline: 4.0481x; 1.1688x over previous
//
#include <hip/hip_runtime.h>

#define D 128

typedef float f32x4 __attribute__((ext_vector_type(4)));
typedef short s16x8 __attribute__((ext_vector_type(8)));

static __device__ __forceinline__ unsigned short f2bf(float f) {
    unsigned int u = __float_as_uint(f);
    unsigned int r = (u + 0x7FFFu + ((u >> 16) & 1u)) >> 16;  // RNE
    return (unsigned short)r;
}

// ===========================================================================
// CSR build (no float atomics)
// ===========================================================================
__global__ void k_hist(const int* __restrict__ dst, int* __restrict__ cnt,
                       int E) {
    int stride = gridDim.x * blockDim.x;
    for (int i = blockIdx.x * blockDim.x + threadIdx.x; i < E; i += stride)
        atomicAdd(&cnt[dst[i]], 1);
}

__global__ void k_alloc(const int* __restrict__ cnt, int* __restrict__ offset,
                        int* __restrict__ cursor, int* __restrict__ gtot,
                        int N) {
    int i = blockIdx.x * blockDim.x + threadIdx.x;
    int lane = threadIdx.x & 63;
    int c = (i < N) ? cnt[i] : 0;
    int s = c;
    #pragma unroll
    for (int o = 1; o < 64; o <<= 1) {
        int t = __shfl_up(s, o);
        if (lane >= o) s += t;
    }
    int wavesum = __shfl(s, 63);
    int base = 0;
    if (lane == 0) base = atomicAdd(gtot, wavesum);
    base = __shfl(base, 0);
    if (i < N) {
        int off = base + s - c;
        offset[i] = off;
        cursor[i] = off;
    }
}

__global__ void k_fill(const int* __restrict__ src, const int* __restrict__ dst,
                       int* __restrict__ cursor, int* __restrict__ srcs,
                       int E) {
    int stride = gridDim.x * blockDim.x;
    for (int i = blockIdx.x * blockDim.x + threadIdx.x; i < E; i += stride) {
        int d = dst[i];
        int p = atomicAdd(&cursor[d], 1);
        srcs[p] = src[i];
    }
}

// ===========================================================================
// Aggregate -> bf16 h.  One wave per node. Lane layout: sub = lane>>5 picks
// one of 2 edges per iteration; cols = 4*(lane&31) (float4 gather).
// ===========================================================================
__global__ __launch_bounds__(256) void k_aggregate_bf16(
    const float* __restrict__ feature, const int* __restrict__ srcs,
    const int* __restrict__ offset, const int* __restrict__ cnt,
    unsigned short* __restrict__ hb, int N) {
    int w = (blockIdx.x * blockDim.x + threadIdx.x) >> 6;
    int lane = threadIdx.x & 63;
    if (w >= N) return;
    int sub = lane >> 5;
    int c0 = (lane & 31) * 4;
    int n = cnt[w];
    f32x4 acc = {0.f, 0.f, 0.f, 0.f};
    if (n == 0) {
        if (sub == 0)
            acc = *reinterpret_cast<const f32x4*>(feature + (size_t)w * D + c0);
    } else {
        int base = offset[w];
        int j = 0;
        for (; j + 4 <= n; j += 4) {
            int s0 = srcs[base + j + sub];
            int s1 = srcs[base + j + 2 + sub];
            f32x4 v0 = *reinterpret_cast<const f32x4*>(feature + (size_t)s0 * D + c0);
            f32x4 v1 = *reinterpret_cast<const f32x4*>(feature + (size_t)s1 * D + c0);
            acc += v0 + v1;
        }
        for (; j < n; j += 2) {
            if (j + sub < n) {
                int s0 = srcs[base + j + sub];
                f32x4 v0 = *reinterpret_cast<const f32x4*>(feature + (size_t)s0 * D + c0);
                acc += v0;
            }
        }
    }
    // combine the two half-wave partials (lane l <-> l^32 hold same cols)
    #pragma unroll
    for (int i = 0; i < 4; ++i) acc[i] += __shfl_xor(acc[i], 32);
    if (n > 1) {
        float r = 1.f / (float)n;
        #pragma unroll
        for (int i = 0; i < 4; ++i) acc[i] *= r;
    }
    if (sub == 0) {
        ushort4 o;
        o.x = f2bf(acc[0]);
        o.y = f2bf(acc[1]);
        o.z = f2bf(acc[2]);
        o.w = f2bf(acc[3]);
        *reinterpret_cast<ushort4*>(hb + (size_t)w * D + c0) = o;
    }
}

// ===========================================================================
// W (fp32, [k][n]) -> Wt (bf16, [n][k])
// ===========================================================================
__global__ void k_wcvt(const float* __restrict__ W,
                       unsigned short* __restrict__ Wt) {
    int o = blockIdx.x * blockDim.x + threadIdx.x;  // o = n*128 + k
    if (o < D * D) {
        int n = o >> 7, k = o & 127;
        Wt[o] = f2bf(W[k * D + n]);
    }
}

// ===========================================================================
// Finalize GEMM: out = relu(h @ W + b), h bf16 [N][128], Wt bf16 [n][k].
// Block = 128 rows x 128 cols, 4 waves (32 rows each). K = 128, one stage.
// LDS: A tile 32KB + Wt 32KB, XOR-swizzled (byte ^= (row&7)<<4).
// ===========================================================================
__global__ __launch_bounds__(256) void k_finalize_mfma(
    const unsigned short* __restrict__ hb, const unsigned short* __restrict__ Wt,
    const float* __restrict__ b, float* __restrict__ out, int N) {
    __shared__ char lds[65536];  // A at 0, B(Wt) at 32768

    int t = threadIdx.x;
    int row0 = blockIdx.x * 128;

    // stage A (h rows row0..row0+127) and B (Wt), 16B per thread per iter
    #pragma unroll
    for (int i = 0; i < 8; ++i) {
        int chunk = i * 256 + t;       // 0..2047
        int row = chunk >> 4;          // 16 x 16B chunks per 256B row
        int c16 = chunk & 15;
        int ldsoff = row * 256 + ((c16 * 16) ^ ((row & 7) << 4));
        f32x4 v = {0.f, 0.f, 0.f, 0.f};
        int grow = row0 + row;
        if (grow < N)
            v = *reinterpret_cast<const f32x4*>(hb + (size_t)grow * D + c16 * 8);
        *reinterpret_cast<f32x4*>(&lds[ldsoff]) = v;
    }
    #pragma unroll
    for (int i = 0; i < 8; ++i) {
        int chunk = i * 256 + t;
        int row = chunk >> 4;
        int c16 = chunk & 15;
        int ldsoff = 32768 + row * 256 + ((c16 * 16) ^ ((row & 7) << 4));
        f32x4 v = *reinterpret_cast<const f32x4*>(Wt + (size_t)row * D + c16 * 8);
        *reinterpret_cast<f32x4*>(&lds[ldsoff]) = v;
    }
    __syncthreads();

    int wv = t >> 6;
    int l = t & 63;
    int l15 = l & 15;
    int lhi = l >> 4;

    f32x4 acc[2][8];
    #pragma unroll
    for (int m = 0; m < 2; ++m)
        #pragma unroll
        for (int n = 0; n < 8; ++n) acc[m][n] = (f32x4){0.f, 0.f, 0.f, 0.f};

    #pragma unroll
    for (int kk = 0; kk < 4; ++kk) {
        int kb = kk * 64 + lhi * 16;  // byte offset of this lane's 8 k-elems
        s16x8 af[2], bf[8];
        #pragma unroll
        for (int m = 0; m < 2; ++m) {
            int r = wv * 32 + m * 16 + l15;
            af[m] = *reinterpret_cast<const s16x8*>(
                &lds[r * 256 + (kb ^ ((r & 7) << 4))]);
        }
        #pragma unroll
        for (int n = 0; n < 8; ++n) {
            int r = n * 16 + l15;
            bf[n] = *reinterpret_cast<const s16x8*>(
                &lds[32768 + r * 256 + (kb ^ ((r & 7) << 4))]);
        }
        #pragma unroll
        for (int m = 0; m < 2; ++m)
            #pragma unroll
            for (int n = 0; n < 8; ++n)
                acc[m][n] = __builtin_amdgcn_mfma_f32_16x16x32_bf16(
                    af[m], bf[n], acc[m][n], 0, 0, 0);
    }

    // epilogue: +b, relu, store fp32.  D layout: col = l&15, row = 4*lhi + j
    #pragma unroll
    for (int n = 0; n < 8; ++n) {
        int col = n * 16 + l15;
        float bv = b[col];
        #pragma unroll
        for (int m = 0; m < 2; ++m) {
            int rbase = row0 + wv * 32 + m * 16 + lhi * 4;
            #pragma unroll
            for (int j = 0; j < 4; ++j) {
                int row = rbase + j;
                if (row < N)
                    out[(size_t)row * D + col] = fmaxf(acc[m][n][j] + bv, 0.f);
            }
        }
    }
}

// ===========================================================================
// Fallback kernels (small workspace tiers)
// ===========================================================================
__global__ __launch_bounds__(256) void k_aggregate_f32(
    const float* __restrict__ feature, const int* __restrict__ srcs,
    const int* __restrict__ offset, const int* __restrict__ cnt,
    float* __restrict__ h, int N) {
    int w = (blockIdx.x * blockDim.x + threadIdx.x) >> 6;
    int lane = threadIdx.x & 63;
    if (w >= N) return;
    int n = cnt[w];
    float2 acc = make_float2(0.f, 0.f);
    if (n == 0) {
        acc = *reinterpret_cast<const float2*>(feature + (size_t)w * D + lane * 2);
    } else {
        int base = offset[w];
        for (int j = 0; j < n; ++j) {
            int s0 = srcs[base + j];
            float2 v0 = *reinterpret_cast<const float2*>(feature + (size_t)s0 * D + lane * 2);
            acc.x += v0.x;
            acc.y += v0.y;
        }
        float r = 1.f / (float)n;
        acc.x *= r;
        acc.y *= r;
    }
    *reinterpret_cast<float2*>(h + (size_t)w * D + lane * 2) = acc;
}

__global__ void gcn_scatter(const float* __restrict__ feature,
                            const int* __restrict__ src,
                            const int* __restrict__ dst,
                            float* __restrict__ agg,
                            float* __restrict__ deg, int n_edges) {
    int gid = blockIdx.x * blockDim.x + threadIdx.x;
    int e = gid >> 6;
    int lane = gid & 63;
    if (e >= n_edges) return;
    int s = src[e];
    int d = dst[e];
    const float2 v =
        *reinterpret_cast<const float2*>(feature + (size_t)s * D + lane * 2);
    float* o = agg + (size_t)d * D + lane * 2;
    atomicAdd(o, v.x);
    atomicAdd(o + 1, v.y);
    if (lane == 0) atomicAdd(deg + d, 1.0f);
}

__global__ __launch_bounds__(256, 2) void gcn_finalize(
    float* __restrict__ inout, const float* __restrict__ feature,
    const float* __restrict__ W, const float* __restrict__ b,
    const float* __restrict__ deg, int n_nodes) {
    __shared__ float Ws[D * D];
    __shared__ float bs[D];
    __shared__ float hs[4][4][D];

    for (int i = threadIdx.x; i < (D * D) / 4; i += blockDim.x)
        reinterpret_cast<float4*>(Ws)[i] = reinterpret_cast<const float4*>(W)[i];
    if (threadIdx.x < D) bs[threadIdx.x] = b[threadIdx.x];
    __syncthreads();

    int wave = threadIdx.x >> 6;
    int lane = threadIdx.x & 63;
    int gwave = (blockIdx.x * blockDim.x + threadIdx.x) >> 6;
    int nwaves = (gridDim.x * blockDim.x) >> 6;
    int ngroups = (n_nodes + 3) / 4;

    for (int g = gwave; g < ngroups; g += nwaves) {
        int row0 = g * 4;
        #pragma unroll
        for (int r = 0; r < 4; ++r) {
            int row = row0 + r;
            if (row < n_nodes) {
                float2 h2;
                if (deg) {
                    float dg = deg[row];
                    if (dg > 0.f) {
                        float2 a = *reinterpret_cast<const float2*>(
                            inout + (size_t)row * D + lane * 2);
                        float rd = 1.f / dg;
                        h2.x = a.x * rd;
                        h2.y = a.y * rd;
                    } else {
                        h2 = *reinterpret_cast<const float2*>(
                            feature + (size_t)row * D + lane * 2);
                    }
                } else {
                    h2 = *reinterpret_cast<const float2*>(
                        inout + (size_t)row * D + lane * 2);
                }
                reinterpret_cast<float2*>(hs[wave][r])[lane] = h2;
            }
        }
        float acc2[4][2];
        #pragma unroll
        for (int r = 0; r < 4; ++r) {
            acc2[r][0] = bs[lane];
            acc2[r][1] = bs[lane + 64];
        }
        #pragma unroll 4
        for (int k = 0; k < D; ++k) {
            float w0 = Ws[k * D + lane];
            float w1 = Ws[k * D + lane + 64];
            #pragma unroll
            for (int r = 0; r < 4; ++r) {
                float hk = hs[wave][r][k];
                acc2[r][0] = fmaf(hk, w0, acc2[r][0]);
                acc2[r][1] = fmaf(hk, w1, acc2[r][1]);
            }
        }
        #pragma unroll
        for (int r = 0; r < 4; ++r) {
            int row = row0 + r;
            if (row < n_nodes) {
                inout[(size_t)row * D + lane] = fmaxf(acc2[r][0], 0.f);
                inout[(size_t)row * D + lane + 64] = fmaxf(acc2[r][1], 0.f);
            }
        }
    }
}

extern "C" void kernel_launch(void* const* d_in, const int* in_sizes, int n_in,
                              void* d_out, int out_size, void* d_ws,
                              size_t ws_size, hipStream_t stream) {
    const float* feature = (const float*)d_in[0];
    const float* W = (const float*)d_in[1];
    const float* b = (const float*)d_in[2];
    const int* src = (const int*)d_in[3];
    const int* dst = (const int*)d_in[4];
    int n_edges = in_sizes[3];
    int n_nodes = in_sizes[0] / D;

    float* out = (float*)d_out;
    int block = 256;

    // ws layout (ints): cnt[N] | gtot[1] | offset[N] | cursor[N] | srcs[E]
    size_t csr_ints = (size_t)3 * n_nodes + 1 + n_edges;
    size_t csr_bytes = csr_ints * sizeof(int);
    size_t hb_off = (csr_bytes + 255) & ~(size_t)255;
    int nrows_pad = ((n_nodes + 127) / 128) * 128;
    size_t hb_bytes = (size_t)nrows_pad * D * sizeof(unsigned short);
    size_t wt_off = hb_off + hb_bytes;
    size_t need_fast = wt_off + (size_t)D * D * sizeof(unsigned short);

    if (ws_size >= need_fast) {
        int* cnt = (int*)d_ws;
        int* gtot = cnt + n_nodes;
        int* offset = gtot + 1;
        int* cursor = offset + n_nodes;
        int* srcs = cursor + n_nodes;
        unsigned short* hb = (unsigned short*)((char*)d_ws + hb_off);
        unsigned short* wt = (unsigned short*)((char*)d_ws + wt_off);

        hipMemsetAsync(cnt, 0, (size_t)(n_nodes + 1) * sizeof(int), stream);
        k_hist<<<2048, block, 0, stream>>>(dst, cnt, n_edges);
        k_alloc<<<(n_nodes + block - 1) / block, block, 0, stream>>>(
            cnt, offset, cursor, gtot, n_nodes);
        k_wcvt<<<(D * D + block - 1) / block, block, 0, stream>>>(W, wt);
        k_fill<<<2048, block, 0, stream>>>(src, dst, cursor, srcs, n_edges);
        k_aggregate_bf16<<<((size_t)n_nodes * 64 + block - 1) / block, block, 0,
                           stream>>>(feature, srcs, offset, cnt, hb, n_nodes);
        k_finalize_mfma<<<(n_nodes + 127) / 128, block, 0, stream>>>(
            hb, wt, b, out, n_nodes);
    } else if (ws_size >= csr_bytes) {
        int* cnt = (int*)d_ws;
        int* gtot = cnt + n_nodes;
        int* offset = gtot + 1;
        int* cursor = offset + n_nodes;
        int* srcs = cursor + n_nodes;

        hipMemsetAsync(cnt, 0, (size_t)(n_nodes + 1) * sizeof(int), stream);
        k_hist<<<2048, block, 0, stream>>>(dst, cnt, n_edges);
        k_alloc<<<(n_nodes + block - 1) / block, block, 0, stream>>>(
            cnt, offset, cursor, gtot, n_nodes);
        k_fill<<<2048, block, 0, stream>>>(src, dst, cursor, srcs, n_edges);
        k_aggregate_f32<<<((size_t)n_nodes * 64 + block - 1) / block, block, 0,
                          stream>>>(feature, srcs, offset, cnt, out, n_nodes);
        gcn_finalize<<<512, block, 0, stream>>>(out, feature, W, b, nullptr,
                                                n_nodes);
    } else {
        float* deg = (float*)d_ws;
        hipMemsetAsync(out, 0, (size_t)out_size * sizeof(float), stream);
        hipMemsetAsync(deg, 0, (size_t)n_nodes * sizeof(float), stream);
        long long total_threads = (long long)n_edges * 64;
        int grid = (int)((total_threads + block - 1) / block);
        gcn_scatter<<<grid, block, 0, stream>>>(feature, src, dst, out, deg,
                                                n_edges);
        gcn_finalize<<<512, block, 0, stream>>>(out, feature, W, b, deg,
                                                n_nodes);
    }
}

// Round 4
// 135.489 us; speedup vs baseline: 4.3479x; 1.0741x over previous
//
#include <hip/hip_runtime.h>

#define D 128

typedef float f32x4 __attribute__((ext_vector_type(4)));
typedef float f32x8 __attribute__((ext_vector_type(8)));
typedef short s16x8 __attribute__((ext_vector_type(8)));
typedef unsigned short u16x8 __attribute__((ext_vector_type(8)));

static __device__ __forceinline__ unsigned short f2bf(float f) {
    unsigned int u = __float_as_uint(f);
    unsigned int r = (u + 0x7FFFu + ((u >> 16) & 1u)) >> 16;  // RNE
    return (unsigned short)r;
}

// ===========================================================================
// ULTRA tier kernels
// ===========================================================================

// hist (4-batched atomics) + feature fp32 -> bf16 conversion, fused
__global__ void k_prep(const int* __restrict__ dst, int* __restrict__ cnt,
                       const float* __restrict__ feature,
                       unsigned short* __restrict__ fb, int E, int NF4) {
    int tid = blockIdx.x * blockDim.x + threadIdx.x;
    int stride = gridDim.x * blockDim.x;
    // histogram, 4 edges per thread per iter
    for (int base = tid * 4; base < E; base += stride * 4) {
        if (base + 4 <= E) {
            int4 d4 = *reinterpret_cast<const int4*>(dst + base);
            atomicAdd(&cnt[d4.x], 1);
            atomicAdd(&cnt[d4.y], 1);
            atomicAdd(&cnt[d4.z], 1);
            atomicAdd(&cnt[d4.w], 1);
        } else {
            for (int i = base; i < E; ++i) atomicAdd(&cnt[dst[i]], 1);
        }
    }
    // feature conversion: float4 -> 4x bf16
    const f32x4* f4 = reinterpret_cast<const f32x4*>(feature);
    ushort4* fb4 = reinterpret_cast<ushort4*>(fb);
    for (int i = tid; i < NF4; i += stride) {
        f32x4 v = f4[i];
        ushort4 o;
        o.x = f2bf(v[0]);
        o.y = f2bf(v[1]);
        o.z = f2bf(v[2]);
        o.w = f2bf(v[3]);
        fb4[i] = o;
    }
}

// bucket base allocation (wave-aggregated atomic bump) + W->Wt bf16 convert
__global__ void k_alloc(const int* __restrict__ cnt, int* __restrict__ offset,
                        int* __restrict__ cursor, int* __restrict__ gtot,
                        int N, const float* __restrict__ W,
                        unsigned short* __restrict__ wt) {
    int i = blockIdx.x * blockDim.x + threadIdx.x;
    int lane = threadIdx.x & 63;
    if (W && i < D * D) {
        int n = i >> 7, k = i & 127;
        wt[i] = f2bf(W[k * D + n]);
    }
    int c = (i < N) ? cnt[i] : 0;
    int s = c;
    #pragma unroll
    for (int o = 1; o < 64; o <<= 1) {
        int t = __shfl_up(s, o);
        if (lane >= o) s += t;
    }
    int wavesum = __shfl(s, 63);
    int base = 0;
    if (lane == 0) base = atomicAdd(gtot, wavesum);
    base = __shfl(base, 0);
    if (i < N) {
        int off = base + s - c;
        offset[i] = off;
        cursor[i] = off;
    }
}

// fill buckets with ushort source ids, 4 edges/thread, nontemporal stores
__global__ void k_fill_u16(const int* __restrict__ src,
                           const int* __restrict__ dst,
                           int* __restrict__ cursor,
                           unsigned short* __restrict__ srcs, int E) {
    int t = blockIdx.x * blockDim.x + threadIdx.x;
    int base = t * 4;
    if (base >= E) return;
    if (base + 4 <= E) {
        int4 d4 = *reinterpret_cast<const int4*>(dst + base);
        int4 s4 = *reinterpret_cast<const int4*>(src + base);
        int p0 = atomicAdd(&cursor[d4.x], 1);
        int p1 = atomicAdd(&cursor[d4.y], 1);
        int p2 = atomicAdd(&cursor[d4.z], 1);
        int p3 = atomicAdd(&cursor[d4.w], 1);
        __builtin_nontemporal_store((unsigned short)s4.x, &srcs[p0]);
        __builtin_nontemporal_store((unsigned short)s4.y, &srcs[p1]);
        __builtin_nontemporal_store((unsigned short)s4.z, &srcs[p2]);
        __builtin_nontemporal_store((unsigned short)s4.w, &srcs[p3]);
    } else {
        for (int i = base; i < E; ++i) {
            int p = atomicAdd(&cursor[dst[i]], 1);
            __builtin_nontemporal_store((unsigned short)src[i], &srcs[p]);
        }
    }
}

static __device__ __forceinline__ void acc_bf16x8(f32x8& acc, u16x8 v) {
    #pragma unroll
    for (int i = 0; i < 8; ++i)
        acc[i] += __uint_as_float(((unsigned int)v[i]) << 16);
}

// aggregate from bf16 feature: one wave per node, 4 edges in flight
// (sub = lane>>4 picks edge, 16 lanes x ushort8 = 256B row)
__global__ __launch_bounds__(256) void k_aggregate_u16(
    const unsigned short* __restrict__ fb, const unsigned short* __restrict__ srcs,
    const int* __restrict__ offset, const int* __restrict__ cnt,
    unsigned short* __restrict__ hb, int N) {
    int w = (blockIdx.x * blockDim.x + threadIdx.x) >> 6;
    int lane = threadIdx.x & 63;
    if (w >= N) return;
    int sub = lane >> 4;
    int l15 = lane & 15;
    int n = cnt[w];
    if (n == 0) {
        // copy own bf16 feature row
        if (sub == 0) {
            u16x8 v = *reinterpret_cast<const u16x8*>(fb + (size_t)w * D + l15 * 8);
            *reinterpret_cast<u16x8*>(hb + (size_t)w * D + l15 * 8) = v;
        }
        return;
    }
    int base = offset[w];
    f32x8 acc = {0.f, 0.f, 0.f, 0.f, 0.f, 0.f, 0.f, 0.f};
    int j = 0;
    for (; j + 8 <= n; j += 8) {
        int s0 = srcs[base + j + sub];
        int s1 = srcs[base + j + 4 + sub];
        u16x8 v0 = *reinterpret_cast<const u16x8*>(fb + (size_t)s0 * D + l15 * 8);
        u16x8 v1 = *reinterpret_cast<const u16x8*>(fb + (size_t)s1 * D + l15 * 8);
        acc_bf16x8(acc, v0);
        acc_bf16x8(acc, v1);
    }
    for (; j < n; j += 4) {
        if (j + sub < n) {
            int s0 = srcs[base + j + sub];
            u16x8 v0 = *reinterpret_cast<const u16x8*>(fb + (size_t)s0 * D + l15 * 8);
            acc_bf16x8(acc, v0);
        }
    }
    // reduce the 4 sub-groups (lanes l, l+16, l+32, l+48 share cols)
    #pragma unroll
    for (int i = 0; i < 8; ++i) acc[i] += __shfl_xor(acc[i], 16);
    #pragma unroll
    for (int i = 0; i < 8; ++i) acc[i] += __shfl_xor(acc[i], 32);
    if (sub == 0) {
        float r = 1.f / (float)n;
        u16x8 o;
        #pragma unroll
        for (int i = 0; i < 8; ++i) o[i] = f2bf(acc[i] * r);
        *reinterpret_cast<u16x8*>(hb + (size_t)w * D + l15 * 8) = o;
    }
}

// ===========================================================================
// Finalize GEMM: out = relu(h @ W + b), h bf16 [N][128], Wt bf16 [n][k].
// Block = 128 rows x 128 cols, 4 waves. LDS XOR-swizzled (byte ^= (row&7)<<4).
// ===========================================================================
__global__ __launch_bounds__(256) void k_finalize_mfma(
    const unsigned short* __restrict__ hb, const unsigned short* __restrict__ Wt,
    const float* __restrict__ b, float* __restrict__ out, int N) {
    __shared__ char lds[65536];  // A at 0, B(Wt) at 32768

    int t = threadIdx.x;
    int row0 = blockIdx.x * 128;

    #pragma unroll
    for (int i = 0; i < 8; ++i) {
        int chunk = i * 256 + t;
        int row = chunk >> 4;
        int c16 = chunk & 15;
        int ldsoff = row * 256 + ((c16 * 16) ^ ((row & 7) << 4));
        f32x4 v = {0.f, 0.f, 0.f, 0.f};
        int grow = row0 + row;
        if (grow < N)
            v = *reinterpret_cast<const f32x4*>(hb + (size_t)grow * D + c16 * 8);
        *reinterpret_cast<f32x4*>(&lds[ldsoff]) = v;
    }
    #pragma unroll
    for (int i = 0; i < 8; ++i) {
        int chunk = i * 256 + t;
        int row = chunk >> 4;
        int c16 = chunk & 15;
        int ldsoff = 32768 + row * 256 + ((c16 * 16) ^ ((row & 7) << 4));
        f32x4 v = *reinterpret_cast<const f32x4*>(Wt + (size_t)row * D + c16 * 8);
        *reinterpret_cast<f32x4*>(&lds[ldsoff]) = v;
    }
    __syncthreads();

    int wv = t >> 6;
    int l = t & 63;
    int l15 = l & 15;
    int lhi = l >> 4;

    f32x4 acc[2][8];
    #pragma unroll
    for (int m = 0; m < 2; ++m)
        #pragma unroll
        for (int n = 0; n < 8; ++n) acc[m][n] = (f32x4){0.f, 0.f, 0.f, 0.f};

    #pragma unroll
    for (int kk = 0; kk < 4; ++kk) {
        int kb = kk * 64 + lhi * 16;
        s16x8 af[2], bf[8];
        #pragma unroll
        for (int m = 0; m < 2; ++m) {
            int r = wv * 32 + m * 16 + l15;
            af[m] = *reinterpret_cast<const s16x8*>(
                &lds[r * 256 + (kb ^ ((r & 7) << 4))]);
        }
        #pragma unroll
        for (int n = 0; n < 8; ++n) {
            int r = n * 16 + l15;
            bf[n] = *reinterpret_cast<const s16x8*>(
                &lds[32768 + r * 256 + (kb ^ ((r & 7) << 4))]);
        }
        #pragma unroll
        for (int m = 0; m < 2; ++m)
            #pragma unroll
            for (int n = 0; n < 8; ++n)
                acc[m][n] = __builtin_amdgcn_mfma_f32_16x16x32_bf16(
                    af[m], bf[n], acc[m][n], 0, 0, 0);
    }

    #pragma unroll
    for (int n = 0; n < 8; ++n) {
        int col = n * 16 + l15;
        float bv = b[col];
        #pragma unroll
        for (int m = 0; m < 2; ++m) {
            int rbase = row0 + wv * 32 + m * 16 + lhi * 4;
            #pragma unroll
            for (int j = 0; j < 4; ++j) {
                int row = rbase + j;
                if (row < N)
                    out[(size_t)row * D + col] = fmaxf(acc[m][n][j] + bv, 0.f);
            }
        }
    }
}

// ===========================================================================
// Tier-2 kernels (round-3 fast path: fp32-feature gather, int srcs)
// ===========================================================================
__global__ void k_hist(const int* __restrict__ dst, int* __restrict__ cnt,
                       int E) {
    int stride = gridDim.x * blockDim.x;
    for (int i = blockIdx.x * blockDim.x + threadIdx.x; i < E; i += stride)
        atomicAdd(&cnt[dst[i]], 1);
}

__global__ void k_fill(const int* __restrict__ src, const int* __restrict__ dst,
                       int* __restrict__ cursor, int* __restrict__ srcs,
                       int E) {
    int stride = gridDim.x * blockDim.x;
    for (int i = blockIdx.x * blockDim.x + threadIdx.x; i < E; i += stride) {
        int d = dst[i];
        int p = atomicAdd(&cursor[d], 1);
        srcs[p] = src[i];
    }
}

__global__ __launch_bounds__(256) void k_aggregate_bf16(
    const float* __restrict__ feature, const int* __restrict__ srcs,
    const int* __restrict__ offset, const int* __restrict__ cnt,
    unsigned short* __restrict__ hb, int N) {
    int w = (blockIdx.x * blockDim.x + threadIdx.x) >> 6;
    int lane = threadIdx.x & 63;
    if (w >= N) return;
    int sub = lane >> 5;
    int c0 = (lane & 31) * 4;
    int n = cnt[w];
    f32x4 acc = {0.f, 0.f, 0.f, 0.f};
    if (n == 0) {
        if (sub == 0)
            acc = *reinterpret_cast<const f32x4*>(feature + (size_t)w * D + c0);
    } else {
        int base = offset[w];
        int j = 0;
        for (; j + 4 <= n; j += 4) {
            int s0 = srcs[base + j + sub];
            int s1 = srcs[base + j + 2 + sub];
            f32x4 v0 = *reinterpret_cast<const f32x4*>(feature + (size_t)s0 * D + c0);
            f32x4 v1 = *reinterpret_cast<const f32x4*>(feature + (size_t)s1 * D + c0);
            acc += v0 + v1;
        }
        for (; j < n; j += 2) {
            if (j + sub < n) {
                int s0 = srcs[base + j + sub];
                f32x4 v0 = *reinterpret_cast<const f32x4*>(feature + (size_t)s0 * D + c0);
                acc += v0;
            }
        }
    }
    #pragma unroll
    for (int i = 0; i < 4; ++i) acc[i] += __shfl_xor(acc[i], 32);
    if (n > 1) {
        float r = 1.f / (float)n;
        #pragma unroll
        for (int i = 0; i < 4; ++i) acc[i] *= r;
    }
    if (sub == 0) {
        ushort4 o;
        o.x = f2bf(acc[0]);
        o.y = f2bf(acc[1]);
        o.z = f2bf(acc[2]);
        o.w = f2bf(acc[3]);
        *reinterpret_cast<ushort4*>(hb + (size_t)w * D + c0) = o;
    }
}

// ===========================================================================
// Tier-3/4 fallbacks
// ===========================================================================
__global__ __launch_bounds__(256) void k_aggregate_f32(
    const float* __restrict__ feature, const int* __restrict__ srcs,
    const int* __restrict__ offset, const int* __restrict__ cnt,
    float* __restrict__ h, int N) {
    int w = (blockIdx.x * blockDim.x + threadIdx.x) >> 6;
    int lane = threadIdx.x & 63;
    if (w >= N) return;
    int n = cnt[w];
    float2 acc = make_float2(0.f, 0.f);
    if (n == 0) {
        acc = *reinterpret_cast<const float2*>(feature + (size_t)w * D + lane * 2);
    } else {
        int base = offset[w];
        for (int j = 0; j < n; ++j) {
            int s0 = srcs[base + j];
            float2 v0 = *reinterpret_cast<const float2*>(feature + (size_t)s0 * D + lane * 2);
            acc.x += v0.x;
            acc.y += v0.y;
        }
        float r = 1.f / (float)n;
        acc.x *= r;
        acc.y *= r;
    }
    *reinterpret_cast<float2*>(h + (size_t)w * D + lane * 2) = acc;
}

__global__ void gcn_scatter(const float* __restrict__ feature,
                            const int* __restrict__ src,
                            const int* __restrict__ dst,
                            float* __restrict__ agg,
                            float* __restrict__ deg, int n_edges) {
    int gid = blockIdx.x * blockDim.x + threadIdx.x;
    int e = gid >> 6;
    int lane = gid & 63;
    if (e >= n_edges) return;
    int s = src[e];
    int d = dst[e];
    const float2 v =
        *reinterpret_cast<const float2*>(feature + (size_t)s * D + lane * 2);
    float* o = agg + (size_t)d * D + lane * 2;
    atomicAdd(o, v.x);
    atomicAdd(o + 1, v.y);
    if (lane == 0) atomicAdd(deg + d, 1.0f);
}

__global__ __launch_bounds__(256, 2) void gcn_finalize(
    float* __restrict__ inout, const float* __restrict__ feature,
    const float* __restrict__ W, const float* __restrict__ b,
    const float* __restrict__ deg, int n_nodes) {
    __shared__ float Ws[D * D];
    __shared__ float bs[D];
    __shared__ float hs[4][4][D];

    for (int i = threadIdx.x; i < (D * D) / 4; i += blockDim.x)
        reinterpret_cast<float4*>(Ws)[i] = reinterpret_cast<const float4*>(W)[i];
    if (threadIdx.x < D) bs[threadIdx.x] = b[threadIdx.x];
    __syncthreads();

    int wave = threadIdx.x >> 6;
    int lane = threadIdx.x & 63;
    int gwave = (blockIdx.x * blockDim.x + threadIdx.x) >> 6;
    int nwaves = (gridDim.x * blockDim.x) >> 6;
    int ngroups = (n_nodes + 3) / 4;

    for (int g = gwave; g < ngroups; g += nwaves) {
        int row0 = g * 4;
        #pragma unroll
        for (int r = 0; r < 4; ++r) {
            int row = row0 + r;
            if (row < n_nodes) {
                float2 h2;
                if (deg) {
                    float dg = deg[row];
                    if (dg > 0.f) {
                        float2 a = *reinterpret_cast<const float2*>(
                            inout + (size_t)row * D + lane * 2);
                        float rd = 1.f / dg;
                        h2.x = a.x * rd;
                        h2.y = a.y * rd;
                    } else {
                        h2 = *reinterpret_cast<const float2*>(
                            feature + (size_t)row * D + lane * 2);
                    }
                } else {
                    h2 = *reinterpret_cast<const float2*>(
                        inout + (size_t)row * D + lane * 2);
                }
                reinterpret_cast<float2*>(hs[wave][r])[lane] = h2;
            }
        }
        float acc2[4][2];
        #pragma unroll
        for (int r = 0; r < 4; ++r) {
            acc2[r][0] = bs[lane];
            acc2[r][1] = bs[lane + 64];
        }
        #pragma unroll 4
        for (int k = 0; k < D; ++k) {
            float w0 = Ws[k * D + lane];
            float w1 = Ws[k * D + lane + 64];
            #pragma unroll
            for (int r = 0; r < 4; ++r) {
                float hk = hs[wave][r][k];
                acc2[r][0] = fmaf(hk, w0, acc2[r][0]);
                acc2[r][1] = fmaf(hk, w1, acc2[r][1]);
            }
        }
        #pragma unroll
        for (int r = 0; r < 4; ++r) {
            int row = row0 + r;
            if (row < n_nodes) {
                inout[(size_t)row * D + lane] = fmaxf(acc2[r][0], 0.f);
                inout[(size_t)row * D + lane + 64] = fmaxf(acc2[r][1], 0.f);
            }
        }
    }
}

extern "C" void kernel_launch(void* const* d_in, const int* in_sizes, int n_in,
                              void* d_out, int out_size, void* d_ws,
                              size_t ws_size, hipStream_t stream) {
    const float* feature = (const float*)d_in[0];
    const float* W = (const float*)d_in[1];
    const float* b = (const float*)d_in[2];
    const int* src = (const int*)d_in[3];
    const int* dst = (const int*)d_in[4];
    int n_edges = in_sizes[3];
    int n_nodes = in_sizes[0] / D;

    float* out = (float*)d_out;
    int block = 256;
    int nrows_pad = ((n_nodes + 127) / 128) * 128;

    // ---- ULTRA layout: cnt[N] gtot[1] offset[N] cursor[N] | srcs u16[E] |
    //      fb u16[N*D] | hb u16[pad*D] | wt u16[D*D]
    size_t ints = (size_t)3 * n_nodes + 1;
    size_t srcs_off = ints * sizeof(int);
    size_t fb_off = (srcs_off + (size_t)n_edges * 2 + 255) & ~(size_t)255;
    size_t hb_off = (fb_off + (size_t)n_nodes * D * 2 + 255) & ~(size_t)255;
    size_t wt_off = hb_off + (size_t)nrows_pad * D * 2;
    size_t need_ultra = wt_off + (size_t)D * D * 2;

    // ---- tier2 layout: cnt gtot offset cursor srcs(int) | hb | wt
    size_t csr_ints = (size_t)3 * n_nodes + 1 + n_edges;
    size_t csr_bytes = csr_ints * sizeof(int);
    size_t t2_hb_off = (csr_bytes + 255) & ~(size_t)255;
    size_t t2_wt_off = t2_hb_off + (size_t)nrows_pad * D * 2;
    size_t need_t2 = t2_wt_off + (size_t)D * D * 2;

    if (n_nodes < 65536 && ws_size >= need_ultra) {
        int* cnt = (int*)d_ws;
        int* gtot = cnt + n_nodes;
        int* offset = gtot + 1;
        int* cursor = offset + n_nodes;
        unsigned short* srcs = (unsigned short*)((char*)d_ws + srcs_off);
        unsigned short* fb = (unsigned short*)((char*)d_ws + fb_off);
        unsigned short* hb = (unsigned short*)((char*)d_ws + hb_off);
        unsigned short* wt = (unsigned short*)((char*)d_ws + wt_off);

        hipMemsetAsync(cnt, 0, (size_t)(n_nodes + 1) * sizeof(int), stream);
        k_prep<<<2048, block, 0, stream>>>(dst, cnt, feature, fb, n_edges,
                                           n_nodes * D / 4);
        k_alloc<<<(n_nodes + block - 1) / block, block, 0, stream>>>(
            cnt, offset, cursor, gtot, n_nodes, W, wt);
        k_fill_u16<<<(n_edges / 4 + block) / block, block, 0, stream>>>(
            src, dst, cursor, srcs, n_edges);
        k_aggregate_u16<<<((size_t)n_nodes * 64 + block - 1) / block, block, 0,
                          stream>>>(fb, srcs, offset, cnt, hb, n_nodes);
        k_finalize_mfma<<<(n_nodes + 127) / 128, block, 0, stream>>>(
            hb, wt, b, out, n_nodes);
    } else if (ws_size >= need_t2) {
        int* cnt = (int*)d_ws;
        int* gtot = cnt + n_nodes;
        int* offset = gtot + 1;
        int* cursor = offset + n_nodes;
        int* srcs = cursor + n_nodes;
        unsigned short* hb = (unsigned short*)((char*)d_ws + t2_hb_off);
        unsigned short* wt = (unsigned short*)((char*)d_ws + t2_wt_off);

        hipMemsetAsync(cnt, 0, (size_t)(n_nodes + 1) * sizeof(int), stream);
        k_hist<<<2048, block, 0, stream>>>(dst, cnt, n_edges);
        k_alloc<<<(n_nodes + block - 1) / block, block, 0, stream>>>(
            cnt, offset, cursor, gtot, n_nodes, W, wt);
        k_fill<<<2048, block, 0, stream>>>(src, dst, cursor, srcs, n_edges);
        k_aggregate_bf16<<<((size_t)n_nodes * 64 + block - 1) / block, block, 0,
                           stream>>>(feature, srcs, offset, cnt, hb, n_nodes);
        k_finalize_mfma<<<(n_nodes + 127) / 128, block, 0, stream>>>(
            hb, wt, b, out, n_nodes);
    } else if (ws_size >= csr_bytes) {
        int* cnt = (int*)d_ws;
        int* gtot = cnt + n_nodes;
        int* offset = gtot + 1;
        int* cursor = offset + n_nodes;
        int* srcs = cursor + n_nodes;

        hipMemsetAsync(cnt, 0, (size_t)(n_nodes + 1) * sizeof(int), stream);
        k_hist<<<2048, block, 0, stream>>>(dst, cnt, n_edges);
        k_alloc<<<(n_nodes + block - 1) / block, block, 0, stream>>>(
            cnt, offset, cursor, gtot, n_nodes, nullptr, nullptr);
        k_fill<<<2048, block, 0, stream>>>(src, dst, cursor, srcs, n_edges);
        k_aggregate_f32<<<((size_t)n_nodes * 64 + block - 1) / block, block, 0,
                          stream>>>(feature, srcs, offset, cnt, out, n_nodes);
        gcn_finalize<<<512, block, 0, stream>>>(out, feature, W, b, nullptr,
                                                n_nodes);
    } else {
        float* deg = (float*)d_ws;
        hipMemsetAsync(out, 0, (size_t)out_size * sizeof(float), stream);
        hipMemsetAsync(deg, 0, (size_t)n_nodes * sizeof(float), stream);
        long long total_threads = (long long)n_edges * 64;
        int grid = (int)((total_threads + block - 1) / block);
        gcn_scatter<<<grid, block, 0, stream>>>(feature, src, dst, out, deg,
                                                n_edges);
        gcn_finalize<<<512, block, 0, stream>>>(out, feature, W, b, deg,
                                                n_nodes);
    }
}